// Round 7
// baseline (3888.950 us; speedup 1.0000x reference)
//
#include <hip/hip_runtime.h>

#define DIM 64
#define NN 20000
#define NE 50000
#define NG 256
#define CONV_STEPS 12
#define S2S 3

typedef float floatx4 __attribute__((ext_vector_type(4)));
typedef float floatx16 __attribute__((ext_vector_type(16)));
typedef short short8 __attribute__((ext_vector_type(8)));

__device__ __forceinline__ unsigned short f2bf(float f) {
    unsigned u = __float_as_uint(f);
    unsigned r = (u + 0x7fffu + ((u >> 16) & 1u)) >> 16;
    return (unsigned short)r;
}
__device__ __forceinline__ float sigmoidf(float x) { return 1.f / (1.f + __expf(-x)); }
__device__ __forceinline__ float tanh_fast(float x) {
    float ax = fabsf(x);
    float t = __expf(-2.f * ax);
    float r = (1.f - t) / (1.f + t);
    return copysignf(r, x);
}
__device__ __forceinline__ float leaky(float v) { return v > 0.f ? v : 0.01f * v; }

// ---- prep: convert net_w2 to bf16, transpose GRU weights ----
__global__ __launch_bounds__(256) void prep_kernel(const float* __restrict__ w2,
        const float* __restrict__ wih, const float* __restrict__ whh,
        unsigned short* __restrict__ w2bf, float* __restrict__ wihT, float* __restrict__ whhT) {
    int idx = blockIdx.x * 256 + threadIdx.x;
    const int W2N = 4096 * 128, GT = 192 * 64;
    if (idx < W2N) {
        w2bf[idx] = f2bf(w2[idx]);
    } else if (idx < W2N + GT) {
        int t = idx - W2N; int j = t / 64, i = t % 64;
        wihT[i * 192 + j] = wih[t];
    } else if (idx < W2N + 2 * GT) {
        int t = idx - W2N - GT; int j = t / 64, i = t % 64;
        whhT[i * 192 + j] = whh[t];
    }
}

// ---- h1 = leaky(edge_attr @ net_w1.T + b1), bf16 [NE,128] ----
__global__ __launch_bounds__(256) void h1_kernel(const float* __restrict__ ea,
        const float* __restrict__ w1, const float* __restrict__ b1, unsigned short* __restrict__ h1) {
    int idx = blockIdx.x * 256 + threadIdx.x;
    if (idx >= NE * 128) return;
    int e = idx >> 7, k = idx & 127;
    const float* a = ea + (size_t)e * 4;
    const float* w = w1 + (size_t)k * 4;
    float acc = b1[k] + a[0] * w[0] + a[1] * w[1] + a[2] * w[2] + a[3] * w[3];
    h1[idx] = f2bf(leaky(acc));
}

// ---- lin0: X = leaky(x @ lin0_w.T + b), f32 [NN,64]; wave per node ----
__global__ __launch_bounds__(256) void lin0_kernel(const float* __restrict__ x,
        const float* __restrict__ w, const float* __restrict__ b, float* __restrict__ X) {
    int gid = blockIdx.x * 256 + threadIdx.x;
    int n = gid >> 6, o = gid & 63;
    if (n >= NN) return;
    float acc = b[o];
    const float* xr = x + (size_t)n * 72;
    const float* wr = w + (size_t)o * 72;
    #pragma unroll 8
    for (int i = 0; i < 72; ++i) acc += xr[i] * wr[i];
    X[(size_t)n * 64 + o] = leaky(acc);
}

// ---- degree of dst nodes ----
__global__ __launch_bounds__(256) void deg_kernel(const int* __restrict__ ei, float* __restrict__ deg) {
    int e = blockIdx.x * 256 + threadIdx.x;
    if (e < NE) atomicAdd(&deg[ei[NE + e]], 1.f);
}

// ---- per-graph node range starts (batch is sorted) ----
__global__ void gstart_kernel(const int* __restrict__ batch, int* __restrict__ gstart) {
    int g = blockIdx.x * blockDim.x + threadIdx.x;
    if (g > NG) return;
    int lo = 0, hi = NN;
    while (lo < hi) { int mid = (lo + hi) >> 1; if (batch[mid] < g) lo = mid + 1; else hi = mid; }
    gstart[g] = lo;
}

// ---- fused edge messages v3: barrier-free K-loop, W2 B-frags straight from
//      L1/L2 into registers, 32x32x16 MFMA.
// grid (ceil(NE/128), 2): y = half of the input-feature (ib) range.
// block 512 thr = 8 waves = (eh in 0..3) x (oh in 0..1).
// wave: 32 edges x 32 o.  Per il: recompute w_e subtile in regs (8 MFMA),
// contract with x from LDS broadcast, accumulate msg; atomics at the end.
__global__ __launch_bounds__(512) void edge_msg_fused(
        const unsigned short* __restrict__ h1,   // [NE,128] bf16
        const unsigned short* __restrict__ w2,   // [4096,128] bf16 (row j=i*64+o)
        const float* __restrict__ b2,            // [4096] f32
        const float* __restrict__ X,             // [NN,64] f32
        const int* __restrict__ ei, float* __restrict__ agg) {
    __shared__ float xs_t[32][128];              // [ib_local][edge_local] 16 KB
    int tid = threadIdx.x;
    int e0b = blockIdx.x * 128;
    int ibBase = blockIdx.y * 32;

    // stage X transposed (f32, broadcast source for the contraction)
    {
        int e_l = tid & 127, q = tid >> 7;       // q in 0..3 -> features q*8..+7
        int e = e0b + e_l; if (e >= NE) e = NE - 1;
        int src = ei[e];
        const float4* xr = (const float4*)(X + (size_t)src * 64 + ibBase + q * 8);
        float4 v0 = xr[0], v1 = xr[1];
        int f0 = q * 8;
        xs_t[f0 + 0][e_l] = v0.x; xs_t[f0 + 1][e_l] = v0.y;
        xs_t[f0 + 2][e_l] = v0.z; xs_t[f0 + 3][e_l] = v0.w;
        xs_t[f0 + 4][e_l] = v1.x; xs_t[f0 + 5][e_l] = v1.y;
        xs_t[f0 + 6][e_l] = v1.z; xs_t[f0 + 7][e_l] = v1.w;
    }

    int wv = tid >> 6, lane = tid & 63;
    int eh = wv >> 1, oh = wv & 1;
    int l31 = lane & 31, l5 = lane >> 5;
    int e0w = e0b + eh * 32;

    // A-frags (h1) hoisted: lane holds edge row l31, k = kc*16 + l5*8 .. +7
    short8 afr[8];
    {
        int e = e0w + l31; if (e >= NE) e = NE - 1;
        const short8* ap = (const short8*)(h1 + (size_t)e * 128 + l5 * 8);
        #pragma unroll
        for (int kc = 0; kc < 8; ++kc) afr[kc] = ap[kc * 2];
    }

    __syncthreads();   // xs_t ready (only barrier in the kernel)

    floatx16 msg;
    #pragma unroll
    for (int r = 0; r < 16; ++r) msg[r] = 0.f;

    for (int il = 0; il < 32; ++il) {
        int ib = ibBase + il;
        int j = ib * 64 + oh * 32 + l31;         // W2 row for this lane
        const short8* bp = (const short8*)(w2 + (size_t)j * 128 + l5 * 8);
        floatx16 acc;
        #pragma unroll
        for (int r = 0; r < 16; ++r) acc[r] = 0.f;
        #pragma unroll
        for (int kc = 0; kc < 8; ++kc)
            acc = __builtin_amdgcn_mfma_f32_32x32x16_bf16(afr[kc], bp[kc * 2], acc, 0, 0, 0);
        float bias = b2[j];
        // x values: edge rows (r&3)+8*(r>>2)+4*l5 -> 4 broadcast float4 reads
        float4 xg[4];
        #pragma unroll
        for (int g = 0; g < 4; ++g)
            xg[g] = *(const float4*)&xs_t[il][eh * 32 + g * 8 + l5 * 4];
        #pragma unroll
        for (int r = 0; r < 16; ++r)
            msg[r] += xg[r >> 2][r & 3] * (acc[r] + bias);
    }

    // scatter-accumulate: lane holds (edge = e0w + (r&3)+8*(r>>2)+4*l5, o = oh*32+l31)
    #pragma unroll
    for (int r = 0; r < 16; ++r) {
        int e = e0w + (r & 3) + 8 * (r >> 2) + 4 * l5;
        if (e < NE) {
            int dst = ei[NE + e];
            atomicAdd(&agg[(size_t)dst * 64 + oh * 32 + l31], msg[r]);
        }
    }
}

// ---- node update: m = leaky(agg/deg + X@root_w + cb); GRU(h=X, in=m) -> X; wave per 4 nodes ----
__global__ __launch_bounds__(256) void node_update(float* __restrict__ X, float* __restrict__ agg,
        const float* __restrict__ deg, const float* __restrict__ root_w, const float* __restrict__ conv_b,
        const float* __restrict__ wihT, const float* __restrict__ whhT,
        const float* __restrict__ bih, const float* __restrict__ bhh) {
    int gid = blockIdx.x * 256 + threadIdx.x;
    int wv = gid >> 6, lane = gid & 63;
    int n0 = wv * 4;
    if (n0 >= NN) return;
    float xv[4], m[4];
    #pragma unroll
    for (int t = 0; t < 4; ++t) xv[t] = X[(size_t)(n0 + t) * 64 + lane];
    float cb = conv_b[lane];
    #pragma unroll
    for (int t = 0; t < 4; ++t) {
        size_t id = (size_t)(n0 + t) * 64 + lane;
        float a = agg[id]; agg[id] = 0.f;   // re-zero for next step's atomics
        m[t] = a / fmaxf(deg[n0 + t], 1.f) + cb;
    }
    #pragma unroll 8
    for (int i = 0; i < 64; ++i) {
        float rw = root_w[i * 64 + lane];
        #pragma unroll
        for (int t = 0; t < 4; ++t) m[t] += __shfl(xv[t], i) * rw;
    }
    #pragma unroll
    for (int t = 0; t < 4; ++t) m[t] = leaky(m[t]);
    float g0[4], g1[4], g2[4], h0[4], h1g[4], h2[4];
    float bi0 = bih[lane], bi1 = bih[64 + lane], bi2 = bih[128 + lane];
    float bh0 = bhh[lane], bh1 = bhh[64 + lane], bh2 = bhh[128 + lane];
    #pragma unroll
    for (int t = 0; t < 4; ++t) { g0[t] = bi0; g1[t] = bi1; g2[t] = bi2; h0[t] = bh0; h1g[t] = bh1; h2[t] = bh2; }
    #pragma unroll 8
    for (int i = 0; i < 64; ++i) {
        float wi0 = wihT[i * 192 + lane], wi1 = wihT[i * 192 + 64 + lane], wi2 = wihT[i * 192 + 128 + lane];
        float wh0 = whhT[i * 192 + lane], wh1 = whhT[i * 192 + 64 + lane], wh2 = whhT[i * 192 + 128 + lane];
        #pragma unroll
        for (int t = 0; t < 4; ++t) {
            float mb = __shfl(m[t], i), hb = __shfl(xv[t], i);
            g0[t] += mb * wi0; g1[t] += mb * wi1; g2[t] += mb * wi2;
            h0[t] += hb * wh0; h1g[t] += hb * wh1; h2[t] += hb * wh2;
        }
    }
    #pragma unroll
    for (int t = 0; t < 4; ++t) {
        float r = sigmoidf(g0[t] + h0[t]);
        float z = sigmoidf(g1[t] + h1g[t]);
        float nn = tanh_fast(g2[t] + r * h2[t]);
        X[(size_t)(n0 + t) * 64 + lane] = (1.f - z) * nn + z * xv[t];
    }
}

// ---- set2set LSTM step; block per graph ----
__global__ __launch_bounds__(256) void lstm_kernel(const float* __restrict__ qstar,
        float* __restrict__ hl, float* __restrict__ cl,
        const float* __restrict__ wih, const float* __restrict__ whh,
        const float* __restrict__ bih, const float* __restrict__ bhh) {
    int g = blockIdx.x, tid = threadIdx.x;
    __shared__ float qs[128], hs[64], gates[256];
    if (tid < 128) qs[tid] = qstar[(size_t)g * 128 + tid];
    else if (tid < 192) hs[tid - 128] = hl[(size_t)g * 64 + tid - 128];
    __syncthreads();
    float acc = bih[tid] + bhh[tid];
    const float* wr = wih + (size_t)tid * 128;
    #pragma unroll 8
    for (int k = 0; k < 128; ++k) acc += qs[k] * wr[k];
    const float* wr2 = whh + (size_t)tid * 64;
    #pragma unroll 8
    for (int k = 0; k < 64; ++k) acc += hs[k] * wr2[k];
    gates[tid] = acc;
    __syncthreads();
    if (tid < 64) {
        float gi = gates[tid], gf = gates[64 + tid], gg = gates[128 + tid], go = gates[192 + tid];
        float c = sigmoidf(gf) * cl[(size_t)g * 64 + tid] + sigmoidf(gi) * tanh_fast(gg);
        float h = sigmoidf(go) * tanh_fast(c);
        cl[(size_t)g * 64 + tid] = c;
        hl[(size_t)g * 64 + tid] = h;
    }
}

// ---- e[n] = dot(X[n], hl[batch[n]]); wave per node ----
__global__ __launch_bounds__(256) void e_kernel(const float* __restrict__ X, const float* __restrict__ hl,
        const int* __restrict__ batch, float* __restrict__ ev) {
    int gid = blockIdx.x * 256 + threadIdx.x;
    int n = gid >> 6, lane = gid & 63;
    if (n >= NN) return;
    int g = batch[n];
    float v = X[(size_t)n * 64 + lane] * hl[(size_t)g * 64 + lane];
    #pragma unroll
    for (int m = 32; m >= 1; m >>= 1) v += __shfl_xor(v, m);
    if (lane == 0) ev[n] = v;
}

// ---- per-graph softmax-attention readout; writes q_star = [hl, r]; block per graph ----
__global__ __launch_bounds__(256) void pool_kernel(const float* __restrict__ X, const float* __restrict__ ev,
        const float* __restrict__ hl, const int* __restrict__ gstart, float* __restrict__ qstar) {
    int g = blockIdx.x, tid = threadIdx.x;
    int s0 = gstart[g], s1 = gstart[g + 1];
    __shared__ float red[256];
    __shared__ float sh_max, sh_sum;
    float lm = -3.0e38f;
    for (int n = s0 + tid; n < s1; n += 256) lm = fmaxf(lm, ev[n]);
    red[tid] = lm; __syncthreads();
    for (int s = 128; s > 0; s >>= 1) { if (tid < s) red[tid] = fmaxf(red[tid], red[tid + s]); __syncthreads(); }
    if (tid == 0) sh_max = red[0];
    __syncthreads();
    float mx = sh_max;
    float ls = 0.f;
    for (int n = s0 + tid; n < s1; n += 256) ls += __expf(ev[n] - mx);
    __syncthreads();
    red[tid] = ls; __syncthreads();
    for (int s = 128; s > 0; s >>= 1) { if (tid < s) red[tid] += red[tid + s]; __syncthreads(); }
    if (tid == 0) sh_sum = red[0];
    __syncthreads();
    float inv = 1.f / (sh_sum + 1e-16f);
    int wv = tid >> 6, lane = tid & 63;
    float fa = 0.f;
    for (int n = s0 + wv; n < s1; n += 4) fa += __expf(ev[n] - mx) * inv * X[(size_t)n * 64 + lane];
    __syncthreads();
    red[tid] = fa; __syncthreads();
    if (tid < 64) {
        float r = red[tid] + red[64 + tid] + red[128 + tid] + red[192 + tid];
        qstar[(size_t)g * 128 + 64 + tid] = r;
        qstar[(size_t)g * 128 + tid] = hl[(size_t)g * 64 + tid];
    }
}

// ---- final: out[g] = q_star[g] . lin3_w + b ----
__global__ __launch_bounds__(256) void final_kernel(const float* __restrict__ qstar,
        const float* __restrict__ w3, const float* __restrict__ b3, float* __restrict__ out) {
    int gid = blockIdx.x * 256 + threadIdx.x;
    int g = gid >> 6, lane = gid & 63;
    if (g >= NG) return;
    float v = qstar[(size_t)g * 128 + lane] * w3[lane] + qstar[(size_t)g * 128 + 64 + lane] * w3[64 + lane];
    #pragma unroll
    for (int m = 32; m >= 1; m >>= 1) v += __shfl_xor(v, m);
    if (lane == 0) out[g] = v + b3[0];
}

extern "C" void kernel_launch(void* const* d_in, const int* in_sizes, int n_in,
                              void* d_out, int out_size, void* d_ws, size_t ws_size,
                              hipStream_t stream) {
    const float* x        = (const float*)d_in[0];
    const float* ea       = (const float*)d_in[1];
    const int*   ei       = (const int*)d_in[2];
    const int*   batch    = (const int*)d_in[3];
    const float* lin0_w   = (const float*)d_in[4];
    const float* lin0_b   = (const float*)d_in[5];
    const float* net_w1   = (const float*)d_in[6];
    const float* net_b1   = (const float*)d_in[7];
    const float* net_w2   = (const float*)d_in[8];
    const float* net_b2   = (const float*)d_in[9];
    const float* root_w   = (const float*)d_in[10];
    const float* conv_b   = (const float*)d_in[11];
    const float* gru_w_ih = (const float*)d_in[12];
    const float* gru_w_hh = (const float*)d_in[13];
    const float* gru_b_ih = (const float*)d_in[14];
    const float* gru_b_hh = (const float*)d_in[15];
    const float* lstm_w_ih= (const float*)d_in[16];
    const float* lstm_w_hh= (const float*)d_in[17];
    const float* lstm_b_ih= (const float*)d_in[18];
    const float* lstm_b_hh= (const float*)d_in[19];
    const float* lin3_w   = (const float*)d_in[20];
    const float* lin3_b   = (const float*)d_in[21];
    float* out = (float*)d_out;

    char* base = (char*)d_ws;
    size_t off = 0;
    auto alloc = [&](size_t b) { size_t o = off; off += (b + 255) & ~(size_t)255; return o; };
    size_t o_h1    = alloc((size_t)NE * 128 * 2);
    size_t o_X     = alloc((size_t)NN * 64 * 4);
    size_t o_agg   = alloc((size_t)NN * 64 * 4);
    size_t o_deg   = alloc((size_t)NN * 4);
    size_t o_ev    = alloc((size_t)NN * 4);
    size_t o_s2s   = alloc((size_t)(NG * 128 + NG * 64 + NG * 64) * 4);  // qstar | hl | cl
    size_t o_gst   = alloc((size_t)(NG + 1) * 4);
    size_t o_w2bf  = alloc((size_t)4096 * 128 * 2);
    size_t o_wihT  = alloc((size_t)192 * 64 * 4);
    size_t o_whhT  = alloc((size_t)192 * 64 * 4);
    if (ws_size < off) return;  // needs ~26 MB

    unsigned short* h1   = (unsigned short*)(base + o_h1);
    float* X    = (float*)(base + o_X);
    float* agg  = (float*)(base + o_agg);
    float* deg  = (float*)(base + o_deg);
    float* ev   = (float*)(base + o_ev);
    float* qstar= (float*)(base + o_s2s);
    float* hl   = qstar + NG * 128;
    float* cl   = hl + NG * 64;
    int*   gst  = (int*)(base + o_gst);
    unsigned short* w2bf = (unsigned short*)(base + o_w2bf);
    float* wihT = (float*)(base + o_wihT);
    float* whhT = (float*)(base + o_whhT);

    hipMemsetAsync(deg, 0, (size_t)NN * 4, stream);
    hipMemsetAsync(agg, 0, (size_t)NN * 64 * 4, stream);
    hipMemsetAsync(qstar, 0, (size_t)(NG * 128 + NG * 64 + NG * 64) * 4, stream);

    prep_kernel<<<(4096 * 128 + 2 * 192 * 64 + 255) / 256, 256, 0, stream>>>(
        net_w2, gru_w_ih, gru_w_hh, w2bf, wihT, whhT);
    h1_kernel<<<(NE * 128 + 255) / 256, 256, 0, stream>>>(ea, net_w1, net_b1, h1);
    lin0_kernel<<<(NN * 64 + 255) / 256, 256, 0, stream>>>(x, lin0_w, lin0_b, X);
    deg_kernel<<<(NE + 255) / 256, 256, 0, stream>>>(ei, deg);
    gstart_kernel<<<2, 256, 0, stream>>>(batch, gst);

    const dim3 EGRID((NE + 127) / 128, 2);
    for (int s = 0; s < CONV_STEPS; ++s) {
        edge_msg_fused<<<EGRID, 512, 0, stream>>>(h1, w2bf, net_b2, X, ei, agg);
        node_update<<<(NN / 4 * 64 + 255) / 256, 256, 0, stream>>>(
            X, agg, deg, root_w, conv_b, wihT, whhT, gru_b_ih, gru_b_hh);
    }

    for (int s = 0; s < S2S; ++s) {
        lstm_kernel<<<NG, 256, 0, stream>>>(qstar, hl, cl, lstm_w_ih, lstm_w_hh, lstm_b_ih, lstm_b_hh);
        e_kernel<<<(NN * 64 + 255) / 256, 256, 0, stream>>>(X, hl, batch, ev);
        pool_kernel<<<NG, 256, 0, stream>>>(X, ev, hl, gst, qstar);
    }
    final_kernel<<<(NG * 64 + 255) / 256, 256, 0, stream>>>(qstar, lin3_w, lin3_b, out);
}

// Round 8
// 2227.825 us; speedup vs baseline: 1.7456x; 1.7456x over previous
//
#include <hip/hip_runtime.h>

#define DIM 64
#define NN 20000
#define NE 50000
#define NG 256
#define CONV_STEPS 12
#define S2S 3

typedef float floatx4 __attribute__((ext_vector_type(4)));
typedef short short8 __attribute__((ext_vector_type(8)));

__device__ __forceinline__ unsigned short f2bf(float f) {
    unsigned u = __float_as_uint(f);
    unsigned r = (u + 0x7fffu + ((u >> 16) & 1u)) >> 16;
    return (unsigned short)r;
}
__device__ __forceinline__ float sigmoidf(float x) { return 1.f / (1.f + __expf(-x)); }
__device__ __forceinline__ float tanh_fast(float x) {
    float ax = fabsf(x);
    float t = __expf(-2.f * ax);
    float r = (1.f - t) / (1.f + t);
    return copysignf(r, x);
}
__device__ __forceinline__ float leaky(float v) { return v > 0.f ? v : 0.01f * v; }

// ---- prep: W2 -> bf16 in MFMA-FRAGMENT ORDER; transpose GRU weights ----
// Fragment order: for o-tile jt (j>>4) and k-chunk kc (k>>5), lane l = kq*16+row
// holds W2[jt*16+row, kc*32+kq*8 .. +8]: flat short index ((jt*4+kc)*64+l)*8+kb.
// A wave's B-frag load is then 64 lanes x 16B contiguous = 1KB coalesced.
__global__ __launch_bounds__(256) void prep_kernel(const float* __restrict__ w2,
        const float* __restrict__ wih, const float* __restrict__ whh,
        unsigned short* __restrict__ w2f, float* __restrict__ wihT, float* __restrict__ whhT) {
    int idx = blockIdx.x * 256 + threadIdx.x;
    const int W2N = 4096 * 128, GT = 192 * 64;
    if (idx < W2N) {
        int j = idx >> 7, k = idx & 127;
        int jt = j >> 4, rw = j & 15;
        int kc = k >> 5, kq = (k >> 3) & 3, kb = k & 7;
        int dst = (((jt * 4 + kc) * 64) + kq * 16 + rw) * 8 + kb;
        w2f[dst] = f2bf(w2[idx]);
    } else if (idx < W2N + GT) {
        int t = idx - W2N; int j = t / 64, i = t % 64;
        wihT[i * 192 + j] = wih[t];
    } else if (idx < W2N + 2 * GT) {
        int t = idx - W2N - GT; int j = t / 64, i = t % 64;
        whhT[i * 192 + j] = whh[t];
    }
}

// ---- h1 = leaky(edge_attr @ net_w1.T + b1), bf16 [NE,128] ----
__global__ __launch_bounds__(256) void h1_kernel(const float* __restrict__ ea,
        const float* __restrict__ w1, const float* __restrict__ b1, unsigned short* __restrict__ h1) {
    int idx = blockIdx.x * 256 + threadIdx.x;
    if (idx >= NE * 128) return;
    int e = idx >> 7, k = idx & 127;
    const float* a = ea + (size_t)e * 4;
    const float* w = w1 + (size_t)k * 4;
    float acc = b1[k] + a[0] * w[0] + a[1] * w[1] + a[2] * w[2] + a[3] * w[3];
    h1[idx] = f2bf(leaky(acc));
}

// ---- lin0: X = leaky(x @ lin0_w.T + b), f32 [NN,64]; wave per node ----
__global__ __launch_bounds__(256) void lin0_kernel(const float* __restrict__ x,
        const float* __restrict__ w, const float* __restrict__ b, float* __restrict__ X) {
    int gid = blockIdx.x * 256 + threadIdx.x;
    int n = gid >> 6, o = gid & 63;
    if (n >= NN) return;
    float acc = b[o];
    const float* xr = x + (size_t)n * 72;
    const float* wr = w + (size_t)o * 72;
    #pragma unroll 8
    for (int i = 0; i < 72; ++i) acc += xr[i] * wr[i];
    X[(size_t)n * 64 + o] = leaky(acc);
}

// ---- XB2[n,o] = sum_i X[n,i] * b2[i*64+o]  (bias term of the message) ----
__global__ __launch_bounds__(256) void xb2_kernel(const float* __restrict__ X,
        const float* __restrict__ b2, float* __restrict__ XB2) {
    int gid = blockIdx.x * 256 + threadIdx.x;
    int n = gid >> 6, lane = gid & 63;
    if (n >= NN) return;
    float xv = X[(size_t)n * 64 + lane];
    float acc = 0.f;
    #pragma unroll 8
    for (int i = 0; i < 64; ++i) acc += __shfl(xv, i) * b2[i * 64 + lane];
    XB2[(size_t)n * 64 + lane] = acc;
}

// ---- degree of dst nodes ----
__global__ __launch_bounds__(256) void deg_kernel(const int* __restrict__ ei, float* __restrict__ deg) {
    int e = blockIdx.x * 256 + threadIdx.x;
    if (e < NE) atomicAdd(&deg[ei[NE + e]], 1.f);
}

// ---- per-graph node range starts (batch is sorted) ----
__global__ void gstart_kernel(const int* __restrict__ batch, int* __restrict__ gstart) {
    int g = blockIdx.x * blockDim.x + threadIdx.x;
    if (g > NG) return;
    int lo = 0, hi = NN;
    while (lo < hi) { int mid = (lo + hi) >> 1; if (batch[mid] < g) lo = mid + 1; else hi = mid; }
    gstart[g] = lo;
}

// ---- fused edge messages v4: barrier-free K-loop; B-frags from global in
//      fragment order (coalesced 1KB/load); bias hoisted to XB2 gather.
// grid (ceil(NE/64), 2): y = half of the input-feature (ib) range.
// block 256 thr = 4 waves, wave = oh quarter: 64 edges x 16 o.
// Per il: 4 coalesced B-frag loads + 4 xs broadcast reads + 16 MFMA + 16 FMA.
__global__ __launch_bounds__(256, 3) void edge_msg_fused(
        const unsigned short* __restrict__ h1,   // [NE,128] bf16
        const unsigned short* __restrict__ w2f,  // [4096,128] bf16, fragment order
        const float* __restrict__ XB2,           // [NN,64] f32 bias term
        const float* __restrict__ X,             // [NN,64] f32
        const int* __restrict__ ei, float* __restrict__ agg) {
    __shared__ float xs_t[32][64];               // [ib_local][edge_local] 8 KB
    int tid = threadIdx.x;
    int e0b = blockIdx.x * 64;
    int ibBase = blockIdx.y * 32;
    bool useBias = (blockIdx.y == 0);

    // stage X transposed: xs_t[f_local][e_local]
    {
        int e_l = tid & 63, q = tid >> 6;        // q 0..3 -> features q*8..+7
        int e = e0b + e_l; if (e >= NE) e = NE - 1;
        int src = ei[e];
        const float4* xr = (const float4*)(X + (size_t)src * 64 + ibBase + q * 8);
        float4 v0 = xr[0], v1 = xr[1];
        int f0 = q * 8;
        xs_t[f0 + 0][e_l] = v0.x; xs_t[f0 + 1][e_l] = v0.y;
        xs_t[f0 + 2][e_l] = v0.z; xs_t[f0 + 3][e_l] = v0.w;
        xs_t[f0 + 4][e_l] = v1.x; xs_t[f0 + 5][e_l] = v1.y;
        xs_t[f0 + 6][e_l] = v1.z; xs_t[f0 + 7][e_l] = v1.w;
    }

    int wv = tid >> 6, lane = tid & 63;
    int oh = wv;                                  // o-quarter
    int row = lane & 15, kq = lane >> 4;

    // A-frags (h1) hoisted: 4 m-tiles x 4 k-chunks (lane: edge=row, k=kc*32+kq*8)
    short8 afr[4][4];
    #pragma unroll
    for (int mt = 0; mt < 4; ++mt) {
        int e = e0b + mt * 16 + row; if (e >= NE) e = NE - 1;
        const short8* ap = (const short8*)(h1 + (size_t)e * 128 + kq * 8);
        #pragma unroll
        for (int kc = 0; kc < 4; ++kc) afr[mt][kc] = ap[kc * 4];
    }

    // msg init = bias gather (XB2[src, o]), only on the y=0 half
    floatx4 msg[4];
    #pragma unroll
    for (int mt = 0; mt < 4; ++mt) {
        #pragma unroll
        for (int r = 0; r < 4; ++r) {
            int e = e0b + mt * 16 + kq * 4 + r; if (e >= NE) e = NE - 1;
            msg[mt][r] = useBias ? XB2[(size_t)ei[e] * 64 + oh * 16 + row] : 0.f;
        }
    }

    __syncthreads();   // xs_t ready (only barrier in the kernel)

    const short8* bbase = (const short8*)w2f;
    for (int il = 0; il < 32; ++il) {
        int tile = (ibBase + il) * 4 + oh;        // 16-row o-tile index
        const short8* bp = bbase + (size_t)tile * 256 + lane;
        short8 bf[4];
        #pragma unroll
        for (int kc = 0; kc < 4; ++kc) bf[kc] = bp[kc * 64];   // coalesced 1KB each
        float4 xv[4];
        #pragma unroll
        for (int mt = 0; mt < 4; ++mt)
            xv[mt] = *(const float4*)&xs_t[il][mt * 16 + kq * 4];
        #pragma unroll
        for (int mt = 0; mt < 4; ++mt) {
            floatx4 acc = {0.f, 0.f, 0.f, 0.f};
            acc = __builtin_amdgcn_mfma_f32_16x16x32_bf16(afr[mt][0], bf[0], acc, 0, 0, 0);
            acc = __builtin_amdgcn_mfma_f32_16x16x32_bf16(afr[mt][1], bf[1], acc, 0, 0, 0);
            acc = __builtin_amdgcn_mfma_f32_16x16x32_bf16(afr[mt][2], bf[2], acc, 0, 0, 0);
            acc = __builtin_amdgcn_mfma_f32_16x16x32_bf16(afr[mt][3], bf[3], acc, 0, 0, 0);
            msg[mt][0] += xv[mt].x * acc[0];
            msg[mt][1] += xv[mt].y * acc[1];
            msg[mt][2] += xv[mt].z * acc[2];
            msg[mt][3] += xv[mt].w * acc[3];
        }
    }

    // scatter-accumulate (lane: edge = mt*16 + kq*4 + r, o = oh*16 + row)
    #pragma unroll
    for (int mt = 0; mt < 4; ++mt) {
        #pragma unroll
        for (int r = 0; r < 4; ++r) {
            int e = e0b + mt * 16 + kq * 4 + r;
            if (e < NE) {
                int dst = ei[NE + e];
                atomicAdd(&agg[(size_t)dst * 64 + oh * 16 + row], msg[mt][r]);
            }
        }
    }
}

// ---- node update: m = leaky(agg/deg + X@root_w + cb); GRU(h=X, in=m) -> X; wave per 4 nodes ----
__global__ __launch_bounds__(256) void node_update(float* __restrict__ X, float* __restrict__ agg,
        const float* __restrict__ deg, const float* __restrict__ root_w, const float* __restrict__ conv_b,
        const float* __restrict__ wihT, const float* __restrict__ whhT,
        const float* __restrict__ bih, const float* __restrict__ bhh) {
    int gid = blockIdx.x * 256 + threadIdx.x;
    int wv = gid >> 6, lane = gid & 63;
    int n0 = wv * 4;
    if (n0 >= NN) return;
    float xv[4], m[4];
    #pragma unroll
    for (int t = 0; t < 4; ++t) xv[t] = X[(size_t)(n0 + t) * 64 + lane];
    float cb = conv_b[lane];
    #pragma unroll
    for (int t = 0; t < 4; ++t) {
        size_t id = (size_t)(n0 + t) * 64 + lane;
        float a = agg[id]; agg[id] = 0.f;   // re-zero for next step's atomics
        m[t] = a / fmaxf(deg[n0 + t], 1.f) + cb;
    }
    #pragma unroll 8
    for (int i = 0; i < 64; ++i) {
        float rw = root_w[i * 64 + lane];
        #pragma unroll
        for (int t = 0; t < 4; ++t) m[t] += __shfl(xv[t], i) * rw;
    }
    #pragma unroll
    for (int t = 0; t < 4; ++t) m[t] = leaky(m[t]);
    float g0[4], g1[4], g2[4], h0[4], h1g[4], h2[4];
    float bi0 = bih[lane], bi1 = bih[64 + lane], bi2 = bih[128 + lane];
    float bh0 = bhh[lane], bh1 = bhh[64 + lane], bh2 = bhh[128 + lane];
    #pragma unroll
    for (int t = 0; t < 4; ++t) { g0[t] = bi0; g1[t] = bi1; g2[t] = bi2; h0[t] = bh0; h1g[t] = bh1; h2[t] = bh2; }
    #pragma unroll 8
    for (int i = 0; i < 64; ++i) {
        float wi0 = wihT[i * 192 + lane], wi1 = wihT[i * 192 + 64 + lane], wi2 = wihT[i * 192 + 128 + lane];
        float wh0 = whhT[i * 192 + lane], wh1 = whhT[i * 192 + 64 + lane], wh2 = whhT[i * 192 + 128 + lane];
        #pragma unroll
        for (int t = 0; t < 4; ++t) {
            float mb = __shfl(m[t], i), hb = __shfl(xv[t], i);
            g0[t] += mb * wi0; g1[t] += mb * wi1; g2[t] += mb * wi2;
            h0[t] += hb * wh0; h1g[t] += hb * wh1; h2[t] += hb * wh2;
        }
    }
    #pragma unroll
    for (int t = 0; t < 4; ++t) {
        float r = sigmoidf(g0[t] + h0[t]);
        float z = sigmoidf(g1[t] + h1g[t]);
        float nn = tanh_fast(g2[t] + r * h2[t]);
        X[(size_t)(n0 + t) * 64 + lane] = (1.f - z) * nn + z * xv[t];
    }
}

// ---- set2set LSTM step; block per graph ----
__global__ __launch_bounds__(256) void lstm_kernel(const float* __restrict__ qstar,
        float* __restrict__ hl, float* __restrict__ cl,
        const float* __restrict__ wih, const float* __restrict__ whh,
        const float* __restrict__ bih, const float* __restrict__ bhh) {
    int g = blockIdx.x, tid = threadIdx.x;
    __shared__ float qs[128], hs[64], gates[256];
    if (tid < 128) qs[tid] = qstar[(size_t)g * 128 + tid];
    else if (tid < 192) hs[tid - 128] = hl[(size_t)g * 64 + tid - 128];
    __syncthreads();
    float acc = bih[tid] + bhh[tid];
    const float* wr = wih + (size_t)tid * 128;
    #pragma unroll 8
    for (int k = 0; k < 128; ++k) acc += qs[k] * wr[k];
    const float* wr2 = whh + (size_t)tid * 64;
    #pragma unroll 8
    for (int k = 0; k < 64; ++k) acc += hs[k] * wr2[k];
    gates[tid] = acc;
    __syncthreads();
    if (tid < 64) {
        float gi = gates[tid], gf = gates[64 + tid], gg = gates[128 + tid], go = gates[192 + tid];
        float c = sigmoidf(gf) * cl[(size_t)g * 64 + tid] + sigmoidf(gi) * tanh_fast(gg);
        float h = sigmoidf(go) * tanh_fast(c);
        cl[(size_t)g * 64 + tid] = c;
        hl[(size_t)g * 64 + tid] = h;
    }
}

// ---- e[n] = dot(X[n], hl[batch[n]]); wave per node ----
__global__ __launch_bounds__(256) void e_kernel(const float* __restrict__ X, const float* __restrict__ hl,
        const int* __restrict__ batch, float* __restrict__ ev) {
    int gid = blockIdx.x * 256 + threadIdx.x;
    int n = gid >> 6, lane = gid & 63;
    if (n >= NN) return;
    int g = batch[n];
    float v = X[(size_t)n * 64 + lane] * hl[(size_t)g * 64 + lane];
    #pragma unroll
    for (int m = 32; m >= 1; m >>= 1) v += __shfl_xor(v, m);
    if (lane == 0) ev[n] = v;
}

// ---- per-graph softmax-attention readout; writes q_star = [hl, r]; block per graph ----
__global__ __launch_bounds__(256) void pool_kernel(const float* __restrict__ X, const float* __restrict__ ev,
        const float* __restrict__ hl, const int* __restrict__ gstart, float* __restrict__ qstar) {
    int g = blockIdx.x, tid = threadIdx.x;
    int s0 = gstart[g], s1 = gstart[g + 1];
    __shared__ float red[256];
    __shared__ float sh_max, sh_sum;
    float lm = -3.0e38f;
    for (int n = s0 + tid; n < s1; n += 256) lm = fmaxf(lm, ev[n]);
    red[tid] = lm; __syncthreads();
    for (int s = 128; s > 0; s >>= 1) { if (tid < s) red[tid] = fmaxf(red[tid], red[tid + s]); __syncthreads(); }
    if (tid == 0) sh_max = red[0];
    __syncthreads();
    float mx = sh_max;
    float ls = 0.f;
    for (int n = s0 + tid; n < s1; n += 256) ls += __expf(ev[n] - mx);
    __syncthreads();
    red[tid] = ls; __syncthreads();
    for (int s = 128; s > 0; s >>= 1) { if (tid < s) red[tid] += red[tid + s]; __syncthreads(); }
    if (tid == 0) sh_sum = red[0];
    __syncthreads();
    float inv = 1.f / (sh_sum + 1e-16f);
    int wv = tid >> 6, lane = tid & 63;
    float fa = 0.f;
    for (int n = s0 + wv; n < s1; n += 4) fa += __expf(ev[n] - mx) * inv * X[(size_t)n * 64 + lane];
    __syncthreads();
    red[tid] = fa; __syncthreads();
    if (tid < 64) {
        float r = red[tid] + red[64 + tid] + red[128 + tid] + red[192 + tid];
        qstar[(size_t)g * 128 + 64 + tid] = r;
        qstar[(size_t)g * 128 + tid] = hl[(size_t)g * 64 + tid];
    }
}

// ---- final: out[g] = q_star[g] . lin3_w + b ----
__global__ __launch_bounds__(256) void final_kernel(const float* __restrict__ qstar,
        const float* __restrict__ w3, const float* __restrict__ b3, float* __restrict__ out) {
    int gid = blockIdx.x * 256 + threadIdx.x;
    int g = gid >> 6, lane = gid & 63;
    if (g >= NG) return;
    float v = qstar[(size_t)g * 128 + lane] * w3[lane] + qstar[(size_t)g * 128 + 64 + lane] * w3[64 + lane];
    #pragma unroll
    for (int m = 32; m >= 1; m >>= 1) v += __shfl_xor(v, m);
    if (lane == 0) out[g] = v + b3[0];
}

extern "C" void kernel_launch(void* const* d_in, const int* in_sizes, int n_in,
                              void* d_out, int out_size, void* d_ws, size_t ws_size,
                              hipStream_t stream) {
    const float* x        = (const float*)d_in[0];
    const float* ea       = (const float*)d_in[1];
    const int*   ei       = (const int*)d_in[2];
    const int*   batch    = (const int*)d_in[3];
    const float* lin0_w   = (const float*)d_in[4];
    const float* lin0_b   = (const float*)d_in[5];
    const float* net_w1   = (const float*)d_in[6];
    const float* net_b1   = (const float*)d_in[7];
    const float* net_w2   = (const float*)d_in[8];
    const float* net_b2   = (const float*)d_in[9];
    const float* root_w   = (const float*)d_in[10];
    const float* conv_b   = (const float*)d_in[11];
    const float* gru_w_ih = (const float*)d_in[12];
    const float* gru_w_hh = (const float*)d_in[13];
    const float* gru_b_ih = (const float*)d_in[14];
    const float* gru_b_hh = (const float*)d_in[15];
    const float* lstm_w_ih= (const float*)d_in[16];
    const float* lstm_w_hh= (const float*)d_in[17];
    const float* lstm_b_ih= (const float*)d_in[18];
    const float* lstm_b_hh= (const float*)d_in[19];
    const float* lin3_w   = (const float*)d_in[20];
    const float* lin3_b   = (const float*)d_in[21];
    float* out = (float*)d_out;

    char* base = (char*)d_ws;
    size_t off = 0;
    auto alloc = [&](size_t b) { size_t o = off; off += (b + 255) & ~(size_t)255; return o; };
    size_t o_h1    = alloc((size_t)NE * 128 * 2);
    size_t o_X     = alloc((size_t)NN * 64 * 4);
    size_t o_agg   = alloc((size_t)NN * 64 * 4);
    size_t o_xb2   = alloc((size_t)NN * 64 * 4);
    size_t o_deg   = alloc((size_t)NN * 4);
    size_t o_ev    = alloc((size_t)NN * 4);
    size_t o_s2s   = alloc((size_t)(NG * 128 + NG * 64 + NG * 64) * 4);  // qstar | hl | cl
    size_t o_gst   = alloc((size_t)(NG + 1) * 4);
    size_t o_w2f   = alloc((size_t)4096 * 128 * 2);
    size_t o_wihT  = alloc((size_t)192 * 64 * 4);
    size_t o_whhT  = alloc((size_t)192 * 64 * 4);
    if (ws_size < off) return;  // needs ~32 MB

    unsigned short* h1   = (unsigned short*)(base + o_h1);
    float* X    = (float*)(base + o_X);
    float* agg  = (float*)(base + o_agg);
    float* XB2  = (float*)(base + o_xb2);
    float* deg  = (float*)(base + o_deg);
    float* ev   = (float*)(base + o_ev);
    float* qstar= (float*)(base + o_s2s);
    float* hl   = qstar + NG * 128;
    float* cl   = hl + NG * 64;
    int*   gst  = (int*)(base + o_gst);
    unsigned short* w2f = (unsigned short*)(base + o_w2f);
    float* wihT = (float*)(base + o_wihT);
    float* whhT = (float*)(base + o_whhT);

    hipMemsetAsync(deg, 0, (size_t)NN * 4, stream);
    hipMemsetAsync(agg, 0, (size_t)NN * 64 * 4, stream);
    hipMemsetAsync(qstar, 0, (size_t)(NG * 128 + NG * 64 + NG * 64) * 4, stream);

    prep_kernel<<<(4096 * 128 + 2 * 192 * 64 + 255) / 256, 256, 0, stream>>>(
        net_w2, gru_w_ih, gru_w_hh, w2f, wihT, whhT);
    h1_kernel<<<(NE * 128 + 255) / 256, 256, 0, stream>>>(ea, net_w1, net_b1, h1);
    lin0_kernel<<<(NN * 64 + 255) / 256, 256, 0, stream>>>(x, lin0_w, lin0_b, X);
    deg_kernel<<<(NE + 255) / 256, 256, 0, stream>>>(ei, deg);
    gstart_kernel<<<2, 256, 0, stream>>>(batch, gst);

    const dim3 EGRID((NE + 63) / 64, 2);
    for (int s = 0; s < CONV_STEPS; ++s) {
        xb2_kernel<<<(NN * 64 + 255) / 256, 256, 0, stream>>>(X, net_b2, XB2);
        edge_msg_fused<<<EGRID, 256, 0, stream>>>(h1, w2f, XB2, X, ei, agg);
        node_update<<<(NN / 4 * 64 + 255) / 256, 256, 0, stream>>>(
            X, agg, deg, root_w, conv_b, wihT, whhT, gru_b_ih, gru_b_hh);
    }

    for (int s = 0; s < S2S; ++s) {
        lstm_kernel<<<NG, 256, 0, stream>>>(qstar, hl, cl, lstm_w_ih, lstm_w_hh, lstm_b_ih, lstm_b_hh);
        e_kernel<<<(NN * 64 + 255) / 256, 256, 0, stream>>>(X, hl, batch, ev);
        pool_kernel<<<NG, 256, 0, stream>>>(X, ev, hl, gst, qstar);
    }
    final_kernel<<<(NG * 64 + 255) / 256, 256, 0, stream>>>(qstar, lin3_w, lin3_b, out);
}